// Round 2
// baseline (888.168 us; speedup 1.0000x reference)
//
#include <hip/hip_runtime.h>
#include <hip/hip_bf16.h>

// ---------------------------------------------------------------------------
// BoundaryConvLayer: fp32 correctness-first implementation.
//   z    = x@W_fc^T + b_fc
//   rate = softplus(x@W_rate^T)
//   h    = softplus(x@W1^T + b1)
//   g_pre= h@W2^T + b2              (stored in d_out, LN'd in final kernel)
//   agg[r] = cnt[r]*z[r] + sum_{edges row=r} z[col]   (CSR bucket, no f32 atomics)
//   out  = LN2( (rate*agg + LN1(g_pre)) / (1 + rate*deg + 1e-4) - z )
// ---------------------------------------------------------------------------

__device__ __forceinline__ float softplus_f(float v) {
    return fmaxf(v, 0.0f) + log1pf(expf(-fabsf(v)));
}

// ---------------- GEMM: C[n][o] = epi( sum_k A[n][k]*W[o][k] (+ bias[o]) ) --
// BM=128, BN=128, BK=16, 256 threads, 8x8 micro-tile per thread.
// EPI: 0 = +bias ; 1 = softplus (no bias) ; 2 = softplus(+bias)
template<int EPI>
__global__ __launch_bounds__(256)
void gemm_epi(const float* __restrict__ A, const float* __restrict__ W,
              const float* __restrict__ bias, float* __restrict__ C,
              int nrows, int ncols, int K)
{
    __shared__ float As[16][128];   // k-major (transposed) for conflict-light reads
    __shared__ float Bs[16][128];
    const int tid = threadIdx.x;
    const int tx = tid & 15;
    const int ty = tid >> 4;
    const int row0 = blockIdx.x * 128;
    const int col0 = blockIdx.y * 128;

    float acc[8][8];
    #pragma unroll
    for (int i = 0; i < 8; ++i)
        #pragma unroll
        for (int j = 0; j < 8; ++j) acc[i][j] = 0.0f;

    for (int k0 = 0; k0 < K; k0 += 16) {
        #pragma unroll
        for (int r = 0; r < 2; ++r) {
            const int idx  = tid + r * 256;      // 0..511
            const int trow = idx >> 2;           // 0..127
            const int kq   = (idx & 3) * 4;      // 0,4,8,12
            float4 av = make_float4(0.f, 0.f, 0.f, 0.f);
            const int ga = row0 + trow;
            if (ga < nrows)
                av = *(const float4*)(A + (size_t)ga * K + k0 + kq);
            As[kq + 0][trow] = av.x; As[kq + 1][trow] = av.y;
            As[kq + 2][trow] = av.z; As[kq + 3][trow] = av.w;
            const float4 wv = *(const float4*)(W + (size_t)(col0 + trow) * K + k0 + kq);
            Bs[kq + 0][trow] = wv.x; Bs[kq + 1][trow] = wv.y;
            Bs[kq + 2][trow] = wv.z; Bs[kq + 3][trow] = wv.w;
        }
        __syncthreads();
        #pragma unroll
        for (int k = 0; k < 16; ++k) {
            float a[8], b[8];
            *(float4*)&a[0] = *(const float4*)&As[k][ty * 8];
            *(float4*)&a[4] = *(const float4*)&As[k][ty * 8 + 4];
            *(float4*)&b[0] = *(const float4*)&Bs[k][tx * 8];
            *(float4*)&b[4] = *(const float4*)&Bs[k][tx * 8 + 4];
            #pragma unroll
            for (int i = 0; i < 8; ++i)
                #pragma unroll
                for (int j = 0; j < 8; ++j)
                    acc[i][j] = fmaf(a[i], b[j], acc[i][j]);
        }
        __syncthreads();
    }

    #pragma unroll
    for (int i = 0; i < 8; ++i) {
        const int grow = row0 + ty * 8 + i;
        if (grow >= nrows) continue;
        #pragma unroll
        for (int jq = 0; jq < 2; ++jq) {
            float4 o;
            float* op = &o.x;
            #pragma unroll
            for (int j = 0; j < 4; ++j) {
                const int gcol = col0 + tx * 8 + jq * 4 + j;
                float v = acc[i][jq * 4 + j];
                if (EPI == 0)      v = v + bias[gcol];
                else if (EPI == 2) v = softplus_f(v + bias[gcol]);
                else               v = softplus_f(v);
                op[j] = v;
            }
            *(float4*)(C + (size_t)grow * ncols + col0 + tx * 8 + jq * 4) = o;
        }
    }
}

// ---------------- edge CSR build ----------------
__global__ void count_edges(const int* __restrict__ ei, int E, int* __restrict__ cnt) {
    for (int e = blockIdx.x * blockDim.x + threadIdx.x; e < E; e += gridDim.x * blockDim.x)
        atomicAdd(&cnt[ei[e]], 1);
}

__global__ void scan_part(const int* __restrict__ cnt, int n, int* __restrict__ part) {
    __shared__ int sdata[256];
    const int base = blockIdx.x * 1024;
    int s = 0;
    for (int i = threadIdx.x; i < 1024; i += 256) {
        const int idx = base + i;
        s += (idx < n) ? cnt[idx] : 0;
    }
    sdata[threadIdx.x] = s;
    __syncthreads();
    for (int st = 128; st > 0; st >>= 1) {
        if (threadIdx.x < st) sdata[threadIdx.x] += sdata[threadIdx.x + st];
        __syncthreads();
    }
    if (threadIdx.x == 0) part[blockIdx.x] = sdata[0];
}

__global__ void scan_top(int* __restrict__ part, int nb) {
    if (threadIdx.x == 0 && blockIdx.x == 0) {
        int run = 0;
        for (int i = 0; i < nb; ++i) { const int v = part[i]; part[i] = run; run += v; }
    }
}

__global__ void scan_final(const int* __restrict__ cnt, int n,
                           const int* __restrict__ part, int* __restrict__ offs) {
    __shared__ int sums[256];
    const int tid = threadIdx.x;
    const int base = blockIdx.x * 1024 + tid * 4;
    int v[4]; int s = 0;
    #pragma unroll
    for (int i = 0; i < 4; ++i) {
        const int idx = base + i;
        v[i] = (idx < n) ? cnt[idx] : 0;
        s += v[i];
    }
    sums[tid] = s;
    __syncthreads();
    for (int st = 1; st < 256; st <<= 1) {
        const int t = (tid >= st) ? sums[tid - st] : 0;
        __syncthreads();
        sums[tid] += t;
        __syncthreads();
    }
    int excl = part[blockIdx.x] + sums[tid] - s;   // exclusive prefix for this chunk
    #pragma unroll
    for (int i = 0; i < 4; ++i) {
        const int idx = base + i;
        if (idx < n) offs[idx] = excl;
        excl += v[i];
    }
}

__global__ void fill_edges(const int* __restrict__ ei, int E, const int* __restrict__ offs,
                           int* __restrict__ cur, int* __restrict__ bucket) {
    for (int e = blockIdx.x * blockDim.x + threadIdx.x; e < E; e += gridDim.x * blockDim.x) {
        const int r = ei[e];
        const int p = atomicAdd(&cur[r], 1);
        bucket[offs[r] + p] = ei[E + e];
    }
}

// ---------------- fused tail: LN1 + gather + combine + LN2 ----------------
__device__ __forceinline__ float wave_allreduce_sum(float v) {
    #pragma unroll
    for (int m = 1; m < 64; m <<= 1) v += __shfl_xor(v, m, 64);
    return v;
}

__global__ __launch_bounds__(256)
void final_fused(const float* __restrict__ z, const float* __restrict__ rate,
                 const float* __restrict__ degree,
                 const int* __restrict__ cnt, const int* __restrict__ offs,
                 const int* __restrict__ bucket,
                 const float* __restrict__ ln1g, const float* __restrict__ ln1b,
                 const float* __restrict__ ln2g, const float* __restrict__ ln2b,
                 float* __restrict__ out, int n)
{
    const int lane = threadIdx.x & 63;
    const int node = blockIdx.x * 4 + (threadIdx.x >> 6);
    if (node >= n) return;

    const float2 zv = ((const float2*)(z    + (size_t)node * 128))[lane];
    const float2 rv = ((const float2*)(rate + (size_t)node * 128))[lane];
    const float2 gp = ((const float2*)(out  + (size_t)node * 128))[lane];  // g_pre

    // LayerNorm 1 -> gamma
    float mean = wave_allreduce_sum(gp.x + gp.y) * (1.0f / 128.0f);
    float d0 = gp.x - mean, d1 = gp.y - mean;
    float var = wave_allreduce_sum(d0 * d0 + d1 * d1) * (1.0f / 128.0f);
    float rstd = rsqrtf(var + 1e-5f);
    const float2 g1 = ((const float2*)ln1g)[lane];
    const float2 b1 = ((const float2*)ln1b)[lane];
    const float gmx = d0 * rstd * g1.x + b1.x;
    const float gmy = d1 * rstd * g1.y + b1.y;

    // aggregate: cnt*z[node] + sum z[col]
    const int c  = cnt[node];
    const int o0 = offs[node];
    float ax = (float)c * zv.x;
    float ay = (float)c * zv.y;
    for (int j = o0; j < o0 + c; ++j) {
        const int col = bucket[j];
        const float2 zc = ((const float2*)(z + (size_t)col * 128))[lane];
        ax += zc.x; ay += zc.y;
    }

    const float dg = degree[node];
    float ox = (rv.x * ax + gmx) / (1.0f + rv.x * dg + 1e-4f) - zv.x;
    float oy = (rv.y * ay + gmy) / (1.0f + rv.y * dg + 1e-4f) - zv.y;

    // LayerNorm 2
    mean = wave_allreduce_sum(ox + oy) * (1.0f / 128.0f);
    d0 = ox - mean; d1 = oy - mean;
    var = wave_allreduce_sum(d0 * d0 + d1 * d1) * (1.0f / 128.0f);
    rstd = rsqrtf(var + 1e-5f);
    const float2 g2 = ((const float2*)ln2g)[lane];
    const float2 b2 = ((const float2*)ln2b)[lane];
    float2 res;
    res.x = d0 * rstd * g2.x + b2.x;
    res.y = d1 * rstd * g2.y + b2.y;
    ((float2*)(out + (size_t)node * 128))[lane] = res;
}

// ---------------------------------------------------------------------------
extern "C" void kernel_launch(void* const* d_in, const int* in_sizes, int n_in,
                              void* d_out, int out_size, void* d_ws, size_t ws_size,
                              hipStream_t stream)
{
    const float* x    = (const float*)d_in[0];
    const int*   ei   = (const int*)  d_in[1];
    const float* deg  = (const float*)d_in[2];
    const float* W_fc = (const float*)d_in[3];
    const float* b_fc = (const float*)d_in[4];
    const float* W_rt = (const float*)d_in[5];
    const float* W1   = (const float*)d_in[6];
    const float* b1   = (const float*)d_in[7];
    const float* W2   = (const float*)d_in[8];
    const float* b2   = (const float*)d_in[9];
    const float* ln1g = (const float*)d_in[10];
    const float* ln1b = (const float*)d_in[11];
    const float* ln2g = (const float*)d_in[12];
    const float* ln2b = (const float*)d_in[13];

    const int N = in_sizes[0] / 128;
    const int E = in_sizes[1] / 2;
    float* out = (float*)d_out;

    // workspace carve (all 16B-aligned by construction)
    char* p = (char*)d_ws;
    float* h  = (float*)p;              p += (size_t)N * 256 * sizeof(float);
    float* z  = h;                      // reused after g_pre GEMM consumes h
    float* rt = h + (size_t)N * 128;
    int* cnt    = (int*)p;              p += (size_t)N * sizeof(int);
    int* cur    = (int*)p;              p += (size_t)N * sizeof(int);
    int* offs   = (int*)p;              p += (size_t)(N + 1) * sizeof(int);
    int* part   = (int*)p;              p += 1024 * sizeof(int);
    int* bucket = (int*)p;              p += (size_t)E * sizeof(int);

    const int nb = (N + 1023) / 1024;

    // edge CSR build (cnt & cur are adjacent -> one memset)
    hipMemsetAsync(cnt, 0, (size_t)2 * N * sizeof(int), stream);
    count_edges<<<2048, 256, 0, stream>>>(ei, E, cnt);
    scan_part <<<nb, 256, 0, stream>>>(cnt, N, part);
    scan_top  <<<1, 64, 0, stream>>>(part, nb);
    scan_final<<<nb, 256, 0, stream>>>(cnt, N, part, offs);
    fill_edges<<<2048, 256, 0, stream>>>(ei, E, offs, cur, bucket);

    // GEMMs (h first; z/rate overwrite h's storage afterwards)
    const int gx = (N + 127) / 128;
    gemm_epi<2><<<dim3(gx, 2), 256, 0, stream>>>(x, W1, b1, h,  N, 256, 128); // h
    gemm_epi<0><<<dim3(gx, 1), 256, 0, stream>>>(h, W2, b2, out, N, 128, 256); // g_pre -> d_out
    gemm_epi<0><<<dim3(gx, 1), 256, 0, stream>>>(x, W_fc, b_fc, z,  N, 128, 128); // z
    gemm_epi<1><<<dim3(gx, 1), 256, 0, stream>>>(x, W_rt, nullptr, rt, N, 128, 128); // rate

    final_fused<<<(N + 3) / 4, 256, 0, stream>>>(z, rt, deg, cnt, offs, bucket,
                                                 ln1g, ln1b, ln2g, ln2b, out, N);
}

// Round 3
// 663.908 us; speedup vs baseline: 1.3378x; 1.3378x over previous
//
#include <hip/hip_runtime.h>
#include <hip/hip_bf16.h>
#include <stdint.h>

// ---------------------------------------------------------------------------
// BoundaryConvLayer — round 3: bf16-MFMA GEMMs + bf16 gather operand.
//   xb   = bf16(x)  (rows padded to N2 = 782*128 with zeros)
//   hb   = bf16(softplus(xb@W1b^T + b1))
//   gpre = hb@W2b^T + b2            -> d_out (guarded), LN'd in final kernel
//   z    = xb@Wfcb^T + b_fc (fp32)  ; zb = bf16(z) (gather operand)
//   rate = softplus(xb@Wrtb^T) (fp32)
//   agg[r] = cnt[r]*z[r] + sum_{edges row=r} zb[col]
//   out  = LN2( (rate*agg + LN1(gpre)) / (1 + rate*deg + 1e-4) - z )
// GEMM: 128x128 tile, BK=128, 4 waves, mfma_f32_16x16x32_bf16,
//       global_load_lds width-16 with XOR granule swizzle on the GLOBAL source
//       (linear LDS dest) and matching XOR on the ds_read_b128 side (rule 21).
// ---------------------------------------------------------------------------

typedef __attribute__((ext_vector_type(8))) short  sh8;
typedef __attribute__((ext_vector_type(4))) float  f32x4;

__device__ __forceinline__ float softplus_f(float v) {
    return fmaxf(v, 0.0f) + log1pf(expf(-fabsf(v)));
}
__device__ __forceinline__ unsigned short f2b(float f) {
    __hip_bfloat16 h = __float2bfloat16(f);
    return *reinterpret_cast<unsigned short*>(&h);
}
__device__ __forceinline__ float b2f(unsigned short u) {
    return __uint_as_float(((unsigned int)u) << 16);
}

// ---------------- conversions ----------------
__global__ __launch_bounds__(256)
void convert_pad(const float* __restrict__ x, unsigned short* __restrict__ xb,
                 long long n_valid, long long n_total)
{
    long long i = ((long long)blockIdx.x * blockDim.x + threadIdx.x) * 8;
    const long long stride = (long long)gridDim.x * blockDim.x * 8;
    for (; i < n_total; i += stride) {
        sh8 o;
        if (i + 8 <= n_valid) {
            const float4 f0 = *(const float4*)(x + i);
            const float4 f1 = *(const float4*)(x + i + 4);
            o[0] = (short)f2b(f0.x); o[1] = (short)f2b(f0.y);
            o[2] = (short)f2b(f0.z); o[3] = (short)f2b(f0.w);
            o[4] = (short)f2b(f1.x); o[5] = (short)f2b(f1.y);
            o[6] = (short)f2b(f1.z); o[7] = (short)f2b(f1.w);
        } else {
            o = (sh8)(short)0;
        }
        *(sh8*)(xb + i) = o;
    }
}

__global__ __launch_bounds__(256)
void convert_weights(const float* __restrict__ Wfc, const float* __restrict__ Wrt,
                     const float* __restrict__ W1,  const float* __restrict__ W2,
                     unsigned short* __restrict__ wb)
{
    const int i = blockIdx.x * blockDim.x + threadIdx.x;   // 0..98303
    float v;
    if (i < 16384)       v = Wfc[i];
    else if (i < 32768)  v = Wrt[i - 16384];
    else if (i < 65536)  v = W1[i - 32768];
    else                 v = W2[i - 65536];
    wb[i] = f2b(v);
}

// ---------------- bf16 MFMA GEMM ----------------
// C[n][o] = epi( sum_k A[n][k]*W[o][k] ), A:[*][K] bf16, W:[ncols][K] bf16.
// EPI: 0 = +bias -> C32 & C16 ; 1 = softplus -> C32 ; 2 = softplus(+bias) -> C16 ;
//      3 = +bias -> C32, rows guarded by nguard.
template<int EPI>
__global__ __launch_bounds__(256)
void gemm_mfma(const unsigned short* __restrict__ A, const unsigned short* __restrict__ W,
               const float* __restrict__ bias,
               float* __restrict__ C32, unsigned short* __restrict__ C16,
               int K, int ldc, int nguard)
{
    __shared__ unsigned short As[128 * 128];
    __shared__ unsigned short Bs[128 * 128];
    const int tid  = threadIdx.x;
    const int lane = tid & 63;
    const int w    = tid >> 6;
    const int wr   = w >> 1, wc = w & 1;      // 2x2 wave grid, 64x64 per wave
    const int row0 = blockIdx.x * 128;
    const int col0 = blockIdx.y * 128;

    f32x4 acc[4][4];
    const f32x4 vzero = {0.f, 0.f, 0.f, 0.f};
    #pragma unroll
    for (int m = 0; m < 4; ++m)
        #pragma unroll
        for (int n = 0; n < 4; ++n) acc[m][n] = vzero;

    for (int kt = 0; kt < K; kt += 128) {
        // stage A tile: 128 rows x 128 cols bf16 (256 B/row = 16 granules of 16 B)
        // source granule = g ^ (row&7), LDS dest linear  (rule 21 both-sides swizzle)
        #pragma unroll
        for (int c = 0; c < 8; ++c) {
            const int idx = c * 256 + tid;          // 0..2047 granules
            const int row = idx >> 4;
            const int gs  = (idx & 15) ^ (row & 7);
            __builtin_amdgcn_global_load_lds(
                (const __attribute__((address_space(1))) void*)(A + (size_t)(row0 + row) * K + kt + gs * 8),
                (__attribute__((address_space(3))) void*)(As + idx * 8), 16, 0, 0);
        }
        #pragma unroll
        for (int c = 0; c < 8; ++c) {
            const int idx = c * 256 + tid;
            const int row = idx >> 4;
            const int gs  = (idx & 15) ^ (row & 7);
            __builtin_amdgcn_global_load_lds(
                (const __attribute__((address_space(1))) void*)(W + (size_t)(col0 + row) * K + kt + gs * 8),
                (__attribute__((address_space(3))) void*)(Bs + idx * 8), 16, 0, 0);
        }
        __syncthreads();

        #pragma unroll
        for (int kk = 0; kk < 4; ++kk) {
            const int gg = kk * 4 + (lane >> 4);    // wanted 16B granule (k-offset/8)
            sh8 a[4], b[4];
            #pragma unroll
            for (int m = 0; m < 4; ++m) {
                const int r = wr * 64 + m * 16 + (lane & 15);
                a[m] = *(const sh8*)(As + r * 128 + ((gg ^ (r & 7)) << 3));
            }
            #pragma unroll
            for (int n = 0; n < 4; ++n) {
                const int r = wc * 64 + n * 16 + (lane & 15);
                b[n] = *(const sh8*)(Bs + r * 128 + ((gg ^ (r & 7)) << 3));
            }
            #pragma unroll
            for (int m = 0; m < 4; ++m)
                #pragma unroll
                for (int n = 0; n < 4; ++n)
                    acc[m][n] = __builtin_amdgcn_mfma_f32_16x16x32_bf16(a[m], b[n], acc[m][n], 0, 0, 0);
        }
        __syncthreads();
    }

    // epilogue: C row = (lane>>4)*4 + r, col = lane&15 within each 16x16 frag
    float bs[4];
    if (EPI == 0 || EPI == 2 || EPI == 3) {
        #pragma unroll
        for (int n = 0; n < 4; ++n)
            bs[n] = bias[col0 + wc * 64 + n * 16 + (lane & 15)];
    }
    #pragma unroll
    for (int m = 0; m < 4; ++m) {
        #pragma unroll
        for (int r = 0; r < 4; ++r) {
            const int grow = row0 + wr * 64 + m * 16 + (lane >> 4) * 4 + r;
            if (EPI == 3 && grow >= nguard) continue;
            #pragma unroll
            for (int n = 0; n < 4; ++n) {
                const int gcol = col0 + wc * 64 + n * 16 + (lane & 15);
                float v = acc[m][n][r];
                if (EPI == 0)      v += bs[n];
                else if (EPI == 1) v = softplus_f(v);
                else if (EPI == 2) v = softplus_f(v + bs[n]);
                else               v += bs[n];
                const size_t o = (size_t)grow * ldc + gcol;
                if (EPI == 0)      { C32[o] = v; C16[o] = f2b(v); }
                else if (EPI == 1) { C32[o] = v; }
                else if (EPI == 2) { C16[o] = f2b(v); }
                else               { C32[o] = v; }
            }
        }
    }
}

// ---------------- edge CSR build ----------------
__global__ void count_edges(const int* __restrict__ ei, int E, int* __restrict__ cnt) {
    for (int e = blockIdx.x * blockDim.x + threadIdx.x; e < E; e += gridDim.x * blockDim.x)
        atomicAdd(&cnt[ei[e]], 1);
}

__global__ void scan_part(const int* __restrict__ cnt, int n, int* __restrict__ part) {
    __shared__ int sdata[256];
    const int base = blockIdx.x * 1024;
    int s = 0;
    for (int i = threadIdx.x; i < 1024; i += 256) {
        const int idx = base + i;
        s += (idx < n) ? cnt[idx] : 0;
    }
    sdata[threadIdx.x] = s;
    __syncthreads();
    for (int st = 128; st > 0; st >>= 1) {
        if (threadIdx.x < st) sdata[threadIdx.x] += sdata[threadIdx.x + st];
        __syncthreads();
    }
    if (threadIdx.x == 0) part[blockIdx.x] = sdata[0];
}

__global__ void scan_top(int* __restrict__ part, int nb) {
    if (threadIdx.x == 0 && blockIdx.x == 0) {
        int run = 0;
        for (int i = 0; i < nb; ++i) { const int v = part[i]; part[i] = run; run += v; }
    }
}

__global__ void scan_final(const int* __restrict__ cnt, int n,
                           const int* __restrict__ part, int* __restrict__ offs) {
    __shared__ int sums[256];
    const int tid = threadIdx.x;
    const int base = blockIdx.x * 1024 + tid * 4;
    int v[4]; int s = 0;
    #pragma unroll
    for (int i = 0; i < 4; ++i) {
        const int idx = base + i;
        v[i] = (idx < n) ? cnt[idx] : 0;
        s += v[i];
    }
    sums[tid] = s;
    __syncthreads();
    for (int st = 1; st < 256; st <<= 1) {
        const int t = (tid >= st) ? sums[tid - st] : 0;
        __syncthreads();
        sums[tid] += t;
        __syncthreads();
    }
    int excl = part[blockIdx.x] + sums[tid] - s;
    #pragma unroll
    for (int i = 0; i < 4; ++i) {
        const int idx = base + i;
        if (idx < n) offs[idx] = excl;
        excl += v[i];
    }
}

__global__ void fill_edges(const int* __restrict__ ei, int E, const int* __restrict__ offs,
                           int* __restrict__ cur, int* __restrict__ bucket) {
    for (int e = blockIdx.x * blockDim.x + threadIdx.x; e < E; e += gridDim.x * blockDim.x) {
        const int r = ei[e];
        const int p = atomicAdd(&cur[r], 1);
        bucket[offs[r] + p] = ei[E + e];
    }
}

// ---------------- fused tail: LN1 + gather + combine + LN2 ----------------
__device__ __forceinline__ float wave_allreduce_sum(float v) {
    #pragma unroll
    for (int m = 1; m < 64; m <<= 1) v += __shfl_xor(v, m, 64);
    return v;
}

__global__ __launch_bounds__(256)
void final_fused(const float* __restrict__ z, const unsigned short* __restrict__ zb,
                 const float* __restrict__ rate, const float* __restrict__ degree,
                 const int* __restrict__ cnt, const int* __restrict__ offs,
                 const int* __restrict__ bucket,
                 const float* __restrict__ ln1g, const float* __restrict__ ln1b,
                 const float* __restrict__ ln2g, const float* __restrict__ ln2b,
                 float* __restrict__ out, int n)
{
    const int lane = threadIdx.x & 63;
    const int node = blockIdx.x * 4 + (threadIdx.x >> 6);
    if (node >= n) return;

    const float2 zv = ((const float2*)(z    + (size_t)node * 128))[lane];
    const float2 rv = ((const float2*)(rate + (size_t)node * 128))[lane];
    const float2 gp = ((const float2*)(out  + (size_t)node * 128))[lane];  // g_pre

    // LayerNorm 1 -> gamma
    float mean = wave_allreduce_sum(gp.x + gp.y) * (1.0f / 128.0f);
    float d0 = gp.x - mean, d1 = gp.y - mean;
    float var = wave_allreduce_sum(d0 * d0 + d1 * d1) * (1.0f / 128.0f);
    float rstd = rsqrtf(var + 1e-5f);
    const float2 g1 = ((const float2*)ln1g)[lane];
    const float2 b1 = ((const float2*)ln1b)[lane];
    const float gmx = d0 * rstd * g1.x + b1.x;
    const float gmy = d1 * rstd * g1.y + b1.y;

    // aggregate: cnt*z[node] (fp32) + sum zb[col] (bf16 gather)
    const int c  = cnt[node];
    const int o0 = offs[node];
    float ax = (float)c * zv.x;
    float ay = (float)c * zv.y;
    for (int j = o0; j < o0 + c; ++j) {
        const int col = bucket[j];
        const unsigned int u = ((const unsigned int*)(zb + (size_t)col * 128))[lane];
        ax += b2f((unsigned short)(u & 0xffffu));
        ay += b2f((unsigned short)(u >> 16));
    }

    const float dg = degree[node];
    float ox = (rv.x * ax + gmx) / (1.0f + rv.x * dg + 1e-4f) - zv.x;
    float oy = (rv.y * ay + gmy) / (1.0f + rv.y * dg + 1e-4f) - zv.y;

    // LayerNorm 2
    mean = wave_allreduce_sum(ox + oy) * (1.0f / 128.0f);
    d0 = ox - mean; d1 = oy - mean;
    var = wave_allreduce_sum(d0 * d0 + d1 * d1) * (1.0f / 128.0f);
    rstd = rsqrtf(var + 1e-5f);
    const float2 g2 = ((const float2*)ln2g)[lane];
    const float2 b2 = ((const float2*)ln2b)[lane];
    float2 res;
    res.x = d0 * rstd * g2.x + b2.x;
    res.y = d1 * rstd * g2.y + b2.y;
    ((float2*)(out + (size_t)node * 128))[lane] = res;
}

// ---------------------------------------------------------------------------
extern "C" void kernel_launch(void* const* d_in, const int* in_sizes, int n_in,
                              void* d_out, int out_size, void* d_ws, size_t ws_size,
                              hipStream_t stream)
{
    const float* x    = (const float*)d_in[0];
    const int*   ei   = (const int*)  d_in[1];
    const float* deg  = (const float*)d_in[2];
    const float* W_fc = (const float*)d_in[3];
    const float* b_fc = (const float*)d_in[4];
    const float* W_rt = (const float*)d_in[5];
    const float* W1   = (const float*)d_in[6];
    const float* b1   = (const float*)d_in[7];
    const float* W2   = (const float*)d_in[8];
    const float* b2   = (const float*)d_in[9];
    const float* ln1g = (const float*)d_in[10];
    const float* ln1b = (const float*)d_in[11];
    const float* ln2g = (const float*)d_in[12];
    const float* ln2b = (const float*)d_in[13];

    const int N  = in_sizes[0] / 128;
    const int E  = in_sizes[1] / 2;
    const int N2 = ((N + 127) / 128) * 128;     // padded rows (100096)
    const int gx = N2 / 128;
    float* out = (float*)d_out;

    // workspace carve
    char* p = (char*)d_ws;
    unsigned short* xb = (unsigned short*)p;  p += (size_t)N2 * 128 * 2;
    unsigned short* hb = (unsigned short*)p;  p += (size_t)N2 * 256 * 2;
    float*          z  = (float*)p;           p += (size_t)N2 * 128 * 4;
    unsigned short* zb = (unsigned short*)p;  p += (size_t)N2 * 128 * 2;
    float*          rt = (float*)p;           p += (size_t)N2 * 128 * 4;
    unsigned short* wb = (unsigned short*)p;  p += 98304 * 2;
    int* cnt    = (int*)p;                    p += (size_t)N * sizeof(int);
    int* cur    = (int*)p;                    p += (size_t)N * sizeof(int);
    int* offs   = (int*)p;                    p += (size_t)(N + 1) * sizeof(int);
    int* part   = (int*)p;                    p += 1024 * sizeof(int);
    int* bucket = (int*)p;

    const int nb = (N + 1023) / 1024;

    // edge CSR build (cnt & cur adjacent -> one memset)
    hipMemsetAsync(cnt, 0, (size_t)2 * N * sizeof(int), stream);
    count_edges<<<2048, 256, 0, stream>>>(ei, E, cnt);
    scan_part <<<nb, 256, 0, stream>>>(cnt, N, part);
    scan_top  <<<1, 64, 0, stream>>>(part, nb);
    scan_final<<<nb, 256, 0, stream>>>(cnt, N, part, offs);
    fill_edges<<<2048, 256, 0, stream>>>(ei, E, offs, cur, bucket);

    // bf16 conversions
    convert_pad    <<<2048, 256, 0, stream>>>(x, xb, (long long)N * 128, (long long)N2 * 128);
    convert_weights<<<384, 256, 0, stream>>>(W_fc, W_rt, W1, W2, wb);

    // GEMMs (MFMA bf16)
    gemm_mfma<2><<<dim3(gx, 2), 256, 0, stream>>>(xb, wb + 32768, b1,   nullptr, hb, 128, 256, N2); // hb
    gemm_mfma<3><<<dim3(gx, 1), 256, 0, stream>>>(hb, wb + 65536, b2,   out, nullptr, 256, 128, N);  // g_pre
    gemm_mfma<0><<<dim3(gx, 1), 256, 0, stream>>>(xb, wb,         b_fc, z,   zb,     128, 128, N2); // z + zb
    gemm_mfma<1><<<dim3(gx, 1), 256, 0, stream>>>(xb, wb + 16384, nullptr, rt, nullptr, 128, 128, N2); // rate

    final_fused<<<(N + 3) / 4, 256, 0, stream>>>(z, zb, rt, deg, cnt, offs, bucket,
                                                 ln1g, ln1b, ln2g, ln2b, out, N);
}

// Round 6
// 553.368 us; speedup vs baseline: 1.6050x; 1.1998x over previous
//
#include <hip/hip_runtime.h>
#include <hip/hip_bf16.h>
#include <stdint.h>

// ---------------------------------------------------------------------------
// BoundaryConvLayer — round 4 (resubmit #2): all-bf16 intermediates, BK=64
// GEMM (5 blk/CU), 4x-unrolled latency-bound gather.
//   xb   = bf16(x) (padded to N2 rows)
//   hb   = bf16(softplus(xb@W1b^T + b1))      [N2 x 256]
//   gpb  = bf16(hb@W2b^T + b2)                [N2 x 128]
//   zb   = bf16(xb@Wfcb^T + b_fc)             [N2 x 128]
//   rtb  = bf16(softplus(xb@Wrtb^T))          [N2 x 128]
//   agg[r] = cnt[r]*zb[r] + sum_{edges row=r} zb[col]
//   out  = LN2( (rtb*agg + LN1(gpb)) / (1 + rtb*deg + 1e-4) - zb )  (fp32)
// ---------------------------------------------------------------------------

typedef __attribute__((ext_vector_type(8))) short  sh8;
typedef __attribute__((ext_vector_type(4))) float  f32x4;

__device__ __forceinline__ float softplus_f(float v) {
    return fmaxf(v, 0.0f) + log1pf(expf(-fabsf(v)));
}
__device__ __forceinline__ unsigned short f2b(float f) {
    __hip_bfloat16 h = __float2bfloat16(f);
    return *reinterpret_cast<unsigned short*>(&h);
}
__device__ __forceinline__ float b2lo(unsigned int u) {
    return __uint_as_float(u << 16);
}
__device__ __forceinline__ float b2hi(unsigned int u) {
    return __uint_as_float(u & 0xffff0000u);
}

// ---------------- conversions ----------------
__global__ __launch_bounds__(256)
void convert_pad(const float* __restrict__ x, unsigned short* __restrict__ xb,
                 long long n_valid, long long n_total)
{
    long long i = ((long long)blockIdx.x * blockDim.x + threadIdx.x) * 8;
    const long long stride = (long long)gridDim.x * blockDim.x * 8;
    for (; i < n_total; i += stride) {
        sh8 o;
        if (i + 8 <= n_valid) {
            const float4 f0 = *(const float4*)(x + i);
            const float4 f1 = *(const float4*)(x + i + 4);
            o[0] = (short)f2b(f0.x); o[1] = (short)f2b(f0.y);
            o[2] = (short)f2b(f0.z); o[3] = (short)f2b(f0.w);
            o[4] = (short)f2b(f1.x); o[5] = (short)f2b(f1.y);
            o[6] = (short)f2b(f1.z); o[7] = (short)f2b(f1.w);
        } else {
            o = (sh8)(short)0;
        }
        *(sh8*)(xb + i) = o;
    }
}

__global__ __launch_bounds__(256)
void convert_weights(const float* __restrict__ Wfc, const float* __restrict__ Wrt,
                     const float* __restrict__ W1,  const float* __restrict__ W2,
                     unsigned short* __restrict__ wb)
{
    const int i = blockIdx.x * blockDim.x + threadIdx.x;   // 0..98303
    float v;
    if (i < 16384)       v = Wfc[i];
    else if (i < 32768)  v = Wrt[i - 16384];
    else if (i < 65536)  v = W1[i - 32768];
    else                 v = W2[i - 65536];
    wb[i] = f2b(v);
}

// ---------------- bf16 MFMA GEMM ----------------
// C16[n][o] = bf16( epi( sum_k A[n][k]*W[o][k] ) ); A:[N2][K], W:[ncols][K].
// 128x128 tile, BK=64 (LDS 32 KB -> 5 blocks/CU), mfma_f32_16x16x32_bf16.
// Both-sides XOR granule swizzle: source granule g^(row&7), linear LDS dest,
// matching XOR on ds_read_b128 (rule 21).
// EPI: 0 = +bias ; 1 = softplus ; 2 = softplus(+bias)
template<int EPI>
__global__ __launch_bounds__(256)
void gemm_mfma(const unsigned short* __restrict__ A, const unsigned short* __restrict__ W,
               const float* __restrict__ bias, unsigned short* __restrict__ C16,
               int K, int ldc)
{
    __shared__ unsigned short As[128 * 64];
    __shared__ unsigned short Bs[128 * 64];
    const int tid  = threadIdx.x;
    const int lane = tid & 63;
    const int w    = tid >> 6;
    const int wr   = w >> 1, wc = w & 1;      // 2x2 wave grid, 64x64 per wave
    const int row0 = blockIdx.x * 128;
    const int col0 = blockIdx.y * 128;

    f32x4 acc[4][4];
    const f32x4 vzero = {0.f, 0.f, 0.f, 0.f};
    #pragma unroll
    for (int m = 0; m < 4; ++m)
        #pragma unroll
        for (int n = 0; n < 4; ++n) acc[m][n] = vzero;

    for (int kt = 0; kt < K; kt += 64) {
        // stage 128 rows x 64 cols bf16 (128 B/row = 8 granules of 16 B) each
        #pragma unroll
        for (int c = 0; c < 4; ++c) {
            const int idx = c * 256 + tid;          // 0..1023 granules
            const int row = idx >> 3;
            const int gs  = (idx & 7) ^ (row & 7);
            __builtin_amdgcn_global_load_lds(
                (const __attribute__((address_space(1))) void*)(A + (size_t)(row0 + row) * K + kt + gs * 8),
                (__attribute__((address_space(3))) void*)(As + idx * 8), 16, 0, 0);
        }
        #pragma unroll
        for (int c = 0; c < 4; ++c) {
            const int idx = c * 256 + tid;
            const int row = idx >> 3;
            const int gs  = (idx & 7) ^ (row & 7);
            __builtin_amdgcn_global_load_lds(
                (const __attribute__((address_space(1))) void*)(W + (size_t)(col0 + row) * K + kt + gs * 8),
                (__attribute__((address_space(3))) void*)(Bs + idx * 8), 16, 0, 0);
        }
        __syncthreads();

        #pragma unroll
        for (int kk = 0; kk < 2; ++kk) {
            const int gg = kk * 4 + (lane >> 4);    // wanted 16B granule (k/8), 0..7
            sh8 a[4], b[4];
            #pragma unroll
            for (int m = 0; m < 4; ++m) {
                const int r = wr * 64 + m * 16 + (lane & 15);
                a[m] = *(const sh8*)(As + r * 64 + ((gg ^ (r & 7)) << 3));
            }
            #pragma unroll
            for (int n = 0; n < 4; ++n) {
                const int r = wc * 64 + n * 16 + (lane & 15);
                b[n] = *(const sh8*)(Bs + r * 64 + ((gg ^ (r & 7)) << 3));
            }
            #pragma unroll
            for (int m = 0; m < 4; ++m)
                #pragma unroll
                for (int n = 0; n < 4; ++n)
                    acc[m][n] = __builtin_amdgcn_mfma_f32_16x16x32_bf16(a[m], b[n], acc[m][n], 0, 0, 0);
        }
        __syncthreads();
    }

    // epilogue: frag row = (lane>>4)*4 + r, col = lane&15
    float bs[4];
    if (EPI == 0 || EPI == 2) {
        #pragma unroll
        for (int n = 0; n < 4; ++n)
            bs[n] = bias[col0 + wc * 64 + n * 16 + (lane & 15)];
    }
    #pragma unroll
    for (int m = 0; m < 4; ++m) {
        #pragma unroll
        for (int r = 0; r < 4; ++r) {
            const int grow = row0 + wr * 64 + m * 16 + (lane >> 4) * 4 + r;
            #pragma unroll
            for (int n = 0; n < 4; ++n) {
                const int gcol = col0 + wc * 64 + n * 16 + (lane & 15);
                float v = acc[m][n][r];
                if (EPI == 0)      v += bs[n];
                else if (EPI == 1) v = softplus_f(v);
                else               v = softplus_f(v + bs[n]);
                C16[(size_t)grow * ldc + gcol] = f2b(v);
            }
        }
    }
}

// ---------------- edge CSR build ----------------
__global__ void count_edges(const int* __restrict__ ei, int E, int* __restrict__ cnt) {
    for (int e = blockIdx.x * blockDim.x + threadIdx.x; e < E; e += gridDim.x * blockDim.x)
        atomicAdd(&cnt[ei[e]], 1);
}

__global__ void scan_part(const int* __restrict__ cnt, int n, int* __restrict__ part) {
    __shared__ int sdata[256];
    const int base = blockIdx.x * 1024;
    int s = 0;
    for (int i = threadIdx.x; i < 1024; i += 256) {
        const int idx = base + i;
        s += (idx < n) ? cnt[idx] : 0;
    }
    sdata[threadIdx.x] = s;
    __syncthreads();
    for (int st = 128; st > 0; st >>= 1) {
        if (threadIdx.x < st) sdata[threadIdx.x] += sdata[threadIdx.x + st];
        __syncthreads();
    }
    if (threadIdx.x == 0) part[blockIdx.x] = sdata[0];
}

// parallel exclusive scan of part[0..nb), nb <= 1024, single block of 256
__global__ __launch_bounds__(256)
void scan_top(int* __restrict__ part, int nb) {
    __shared__ int sums[256];
    const int tid = threadIdx.x;
    int v[4]; int s = 0;
    #pragma unroll
    for (int i = 0; i < 4; ++i) {
        const int idx = tid * 4 + i;
        v[i] = (idx < nb) ? part[idx] : 0;
        s += v[i];
    }
    sums[tid] = s;
    __syncthreads();
    for (int st = 1; st < 256; st <<= 1) {
        const int t = (tid >= st) ? sums[tid - st] : 0;
        __syncthreads();
        sums[tid] += t;
        __syncthreads();
    }
    int excl = sums[tid] - s;
    #pragma unroll
    for (int i = 0; i < 4; ++i) {
        const int idx = tid * 4 + i;
        if (idx < nb) part[idx] = excl;
        excl += v[i];
    }
}

__global__ void scan_final(const int* __restrict__ cnt, int n,
                           const int* __restrict__ part, int* __restrict__ offs) {
    __shared__ int sums[256];
    const int tid = threadIdx.x;
    const int base = blockIdx.x * 1024 + tid * 4;
    int v[4]; int s = 0;
    #pragma unroll
    for (int i = 0; i < 4; ++i) {
        const int idx = base + i;
        v[i] = (idx < n) ? cnt[idx] : 0;
        s += v[i];
    }
    sums[tid] = s;
    __syncthreads();
    for (int st = 1; st < 256; st <<= 1) {
        const int t = (tid >= st) ? sums[tid - st] : 0;
        __syncthreads();
        sums[tid] += t;
        __syncthreads();
    }
    int excl = part[blockIdx.x] + sums[tid] - s;
    #pragma unroll
    for (int i = 0; i < 4; ++i) {
        const int idx = base + i;
        if (idx < n) offs[idx] = excl;
        excl += v[i];
    }
}

__global__ void fill_edges(const int* __restrict__ ei, int E, const int* __restrict__ offs,
                           int* __restrict__ cur, int* __restrict__ bucket) {
    for (int e = blockIdx.x * blockDim.x + threadIdx.x; e < E; e += gridDim.x * blockDim.x) {
        const int r = ei[e];
        const int p = atomicAdd(&cur[r], 1);
        bucket[offs[r] + p] = ei[E + e];
    }
}

// ---------------- fused tail: LN1 + gather + combine + LN2 ----------------
__device__ __forceinline__ float wave_allreduce_sum(float v) {
    #pragma unroll
    for (int m = 1; m < 64; m <<= 1) v += __shfl_xor(v, m, 64);
    return v;
}

__global__ __launch_bounds__(256)
void final_fused(const unsigned short* __restrict__ zb, const unsigned short* __restrict__ rtb,
                 const unsigned short* __restrict__ gpb, const float* __restrict__ degree,
                 const int* __restrict__ cnt, const int* __restrict__ offs,
                 const int* __restrict__ bucket,
                 const float* __restrict__ ln1g, const float* __restrict__ ln1b,
                 const float* __restrict__ ln2g, const float* __restrict__ ln2b,
                 float* __restrict__ out, int n)
{
    const int lane = threadIdx.x & 63;
    const int node = blockIdx.x * 4 + (threadIdx.x >> 6);
    if (node >= n) return;

    const unsigned int uz = ((const unsigned int*)(zb  + (size_t)node * 128))[lane];
    const unsigned int ur = ((const unsigned int*)(rtb + (size_t)node * 128))[lane];
    const unsigned int ug = ((const unsigned int*)(gpb + (size_t)node * 128))[lane];
    const float zx = b2lo(uz), zy = b2hi(uz);
    const float rx = b2lo(ur), ry = b2hi(ur);
    const float px = b2lo(ug), py = b2hi(ug);

    // LayerNorm 1 -> gamma
    float mean = wave_allreduce_sum(px + py) * (1.0f / 128.0f);
    float d0 = px - mean, d1 = py - mean;
    float var = wave_allreduce_sum(d0 * d0 + d1 * d1) * (1.0f / 128.0f);
    float rstd = rsqrtf(var + 1e-5f);
    const float2 g1 = ((const float2*)ln1g)[lane];
    const float2 b1 = ((const float2*)ln1b)[lane];
    const float gmx = d0 * rstd * g1.x + b1.x;
    const float gmy = d1 * rstd * g1.y + b1.y;

    // aggregate: cnt*z[node] + sum zb[col]  (4x unrolled, 2 acc pairs for MLP)
    const int c    = cnt[node];
    const int o0   = offs[node];
    const int jend = o0 + c;
    float ax = (float)c * zx, ay = (float)c * zy;
    float bx = 0.0f, by = 0.0f;
    int j = o0;
    for (; j + 4 <= jend; j += 4) {
        const int c0 = bucket[j + 0];
        const int c1 = bucket[j + 1];
        const int c2 = bucket[j + 2];
        const int c3 = bucket[j + 3];
        const unsigned int u0 = ((const unsigned int*)(zb + (size_t)c0 * 128))[lane];
        const unsigned int u1 = ((const unsigned int*)(zb + (size_t)c1 * 128))[lane];
        const unsigned int u2 = ((const unsigned int*)(zb + (size_t)c2 * 128))[lane];
        const unsigned int u3 = ((const unsigned int*)(zb + (size_t)c3 * 128))[lane];
        ax += b2lo(u0) + b2lo(u2);
        ay += b2hi(u0) + b2hi(u2);
        bx += b2lo(u1) + b2lo(u3);
        by += b2hi(u1) + b2hi(u3);
    }
    for (; j < jend; ++j) {
        const int c0 = bucket[j];
        const unsigned int u0 = ((const unsigned int*)(zb + (size_t)c0 * 128))[lane];
        ax += b2lo(u0);
        ay += b2hi(u0);
    }
    ax += bx; ay += by;

    const float dg = degree[node];
    float ox = (rx * ax + gmx) / (1.0f + rx * dg + 1e-4f) - zx;
    float oy = (ry * ay + gmy) / (1.0f + ry * dg + 1e-4f) - zy;

    // LayerNorm 2
    mean = wave_allreduce_sum(ox + oy) * (1.0f / 128.0f);
    d0 = ox - mean; d1 = oy - mean;
    var = wave_allreduce_sum(d0 * d0 + d1 * d1) * (1.0f / 128.0f);
    rstd = rsqrtf(var + 1e-5f);
    const float2 g2 = ((const float2*)ln2g)[lane];
    const float2 b2 = ((const float2*)ln2b)[lane];
    float2 res;
    res.x = d0 * rstd * g2.x + b2.x;
    res.y = d1 * rstd * g2.y + b2.y;
    ((float2*)(out + (size_t)node * 128))[lane] = res;
}

// ---------------------------------------------------------------------------
extern "C" void kernel_launch(void* const* d_in, const int* in_sizes, int n_in,
                              void* d_out, int out_size, void* d_ws, size_t ws_size,
                              hipStream_t stream)
{
    const float* x    = (const float*)d_in[0];
    const int*   ei   = (const int*)  d_in[1];
    const float* deg  = (const float*)d_in[2];
    const float* W_fc = (const float*)d_in[3];
    const float* b_fc = (const float*)d_in[4];
    const float* W_rt = (const float*)d_in[5];
    const float* W1   = (const float*)d_in[6];
    const float* b1   = (const float*)d_in[7];
    const float* W2   = (const float*)d_in[8];
    const float* b2   = (const float*)d_in[9];
    const float* ln1g = (const float*)d_in[10];
    const float* ln1b = (const float*)d_in[11];
    const float* ln2g = (const float*)d_in[12];
    const float* ln2b = (const float*)d_in[13];

    const int N  = in_sizes[0] / 128;
    const int E  = in_sizes[1] / 2;
    const int N2 = ((N + 127) / 128) * 128;     // padded rows
    const int gx = N2 / 128;
    float* out = (float*)d_out;

    // workspace carve (16B-aligned by construction)
    char* p = (char*)d_ws;
    unsigned short* xb  = (unsigned short*)p;  p += (size_t)N2 * 128 * 2;
    unsigned short* hb  = (unsigned short*)p;  p += (size_t)N2 * 256 * 2;
    unsigned short* zb  = (unsigned short*)p;  p += (size_t)N2 * 128 * 2;
    unsigned short* rtb = (unsigned short*)p;  p += (size_t)N2 * 128 * 2;
    unsigned short* gpb = (unsigned short*)p;  p += (size_t)N2 * 128 * 2;
    unsigned short* wb  = (unsigned short*)p;  p += 98304 * 2;
    int* cnt    = (int*)p;                     p += (size_t)N * sizeof(int);
    int* cur    = (int*)p;                     p += (size_t)N * sizeof(int);
    int* offs   = (int*)p;                     p += (size_t)(N + 1) * sizeof(int);
    int* part   = (int*)p;                     p += 1024 * sizeof(int);
    int* bucket = (int*)p;

    const int nb = (N + 1023) / 1024;

    // edge CSR build (cnt & cur adjacent -> one memset)
    hipMemsetAsync(cnt, 0, (size_t)2 * N * sizeof(int), stream);
    count_edges<<<2048, 256, 0, stream>>>(ei, E, cnt);
    scan_part <<<nb, 256, 0, stream>>>(cnt, N, part);
    scan_top  <<<1, 256, 0, stream>>>(part, nb);
    scan_final<<<nb, 256, 0, stream>>>(cnt, N, part, offs);
    fill_edges<<<2048, 256, 0, stream>>>(ei, E, offs, cur, bucket);

    // bf16 conversions
    convert_pad    <<<2048, 256, 0, stream>>>(x, xb, (long long)N * 128, (long long)N2 * 128);
    convert_weights<<<384, 256, 0, stream>>>(W_fc, W_rt, W1, W2, wb);

    // GEMMs (MFMA bf16, all outputs bf16 in padded ws)
    gemm_mfma<2><<<dim3(gx, 2), 256, 0, stream>>>(xb, wb + 32768, b1,   hb,  128, 256); // hb
    gemm_mfma<0><<<dim3(gx, 1), 256, 0, stream>>>(hb, wb + 65536, b2,   gpb, 256, 128); // g_pre
    gemm_mfma<0><<<dim3(gx, 1), 256, 0, stream>>>(xb, wb,         b_fc, zb,  128, 128); // z
    gemm_mfma<1><<<dim3(gx, 1), 256, 0, stream>>>(xb, wb + 16384, nullptr, rtb, 128, 128); // rate

    final_fused<<<(N + 3) / 4, 256, 0, stream>>>(zb, rtb, gpb, deg, cnt, offs, bucket,
                                                 ln1g, ln1b, ln2g, ln2b, out, N);
}

// Round 7
// 450.044 us; speedup vs baseline: 1.9735x; 1.2296x over previous
//
#include <hip/hip_runtime.h>
#include <hip/hip_bf16.h>
#include <stdint.h>

// ---------------------------------------------------------------------------
// BoundaryConvLayer — round 7: kill the VALU-bound GEMM epilogue.
//   (round-6 PMC: hb GEMM VALUBusy=96%, MfmaUtil=2.8% -> libm softplus +
//    __float2bfloat16 in the epilogue dominated. Replace with hw exp/log +
//    manual RTE pack; merge z/rate/hb panels into one dispatch.)
//   xb   = bf16(x) (padded to N2 rows)
//   fused3: by=0 -> zb = xb@Wfc^T + b_fc
//           by=1 -> rtb = softplus(xb@Wrt^T)
//           by=2,3 -> hb = softplus(xb@W1^T + b1)   [N2 x 256]
//   gpre : gpb = hb@W2^T + b2                       [N2 x 128]
//   agg[r] = cnt[r]*zb[r] + sum_{edges row=r} zb[col]
//   out  = LN2( (rtb*agg + LN1(gpb)) / (1 + rtb*deg + 1e-4) - zb )  (fp32)
// ---------------------------------------------------------------------------

typedef __attribute__((ext_vector_type(8))) short  sh8;
typedef __attribute__((ext_vector_type(4))) float  f32x4;

// fast softplus: hw v_exp_f32 / v_log_f32 (~8 VALU ops, |err| ~1e-6)
__device__ __forceinline__ float softplus_fast(float v) {
    const float t = __expf(-fabsf(v));
    return fmaxf(v, 0.0f) + __logf(1.0f + t);
}
// manual round-to-nearest-even bf16 pack (4 VALU ops, no libm)
__device__ __forceinline__ unsigned short f2b(float f) {
    unsigned int u = __float_as_uint(f);
    u += 0x7fffu + ((u >> 16) & 1u);
    return (unsigned short)(u >> 16);
}
__device__ __forceinline__ float b2lo(unsigned int u) {
    return __uint_as_float(u << 16);
}
__device__ __forceinline__ float b2hi(unsigned int u) {
    return __uint_as_float(u & 0xffff0000u);
}

// ---------------- conversions ----------------
__global__ __launch_bounds__(256)
void convert_pad(const float* __restrict__ x, unsigned short* __restrict__ xb,
                 long long n_valid, long long n_total)
{
    long long i = ((long long)blockIdx.x * blockDim.x + threadIdx.x) * 8;
    const long long stride = (long long)gridDim.x * blockDim.x * 8;
    for (; i < n_total; i += stride) {
        sh8 o;
        if (i + 8 <= n_valid) {
            const float4 f0 = *(const float4*)(x + i);
            const float4 f1 = *(const float4*)(x + i + 4);
            o[0] = (short)f2b(f0.x); o[1] = (short)f2b(f0.y);
            o[2] = (short)f2b(f0.z); o[3] = (short)f2b(f0.w);
            o[4] = (short)f2b(f1.x); o[5] = (short)f2b(f1.y);
            o[6] = (short)f2b(f1.z); o[7] = (short)f2b(f1.w);
        } else {
            o = (sh8)(short)0;
        }
        *(sh8*)(xb + i) = o;
    }
}

__global__ __launch_bounds__(256)
void convert_weights(const float* __restrict__ Wfc, const float* __restrict__ Wrt,
                     const float* __restrict__ W1,  const float* __restrict__ W2,
                     unsigned short* __restrict__ wb)
{
    const int i = blockIdx.x * blockDim.x + threadIdx.x;   // 0..98303
    float v;
    if (i < 16384)       v = Wfc[i];
    else if (i < 32768)  v = Wrt[i - 16384];
    else if (i < 65536)  v = W1[i - 32768];
    else                 v = W2[i - 65536];
    wb[i] = f2b(v);
}

// ---------------- GEMM core macro-helpers (verified r3/r6 structure) -------
// 128x128 tile, BK=64, 4 waves, mfma_f32_16x16x32_bf16; both-sides XOR
// granule swizzle: global source granule g^(row&7), linear LDS dest,
// matching XOR on the ds_read_b128 side (rule 21).

// fused z/rate/hb panels: W = wb rows [by*128, by*128+128) of [Wfc|Wrt|W1]
__global__ __launch_bounds__(256)
void gemm_fused3(const unsigned short* __restrict__ A, const unsigned short* __restrict__ Wcat,
                 const float* __restrict__ b_fc, const float* __restrict__ b1,
                 unsigned short* __restrict__ zbuf, unsigned short* __restrict__ rbuf,
                 unsigned short* __restrict__ hbuf)
{
    __shared__ unsigned short As[128 * 64];
    __shared__ unsigned short Bs[128 * 64];
    const int tid  = threadIdx.x;
    const int lane = tid & 63;
    const int w    = tid >> 6;
    const int wr   = w >> 1, wc = w & 1;
    const int row0 = blockIdx.x * 128;
    const int by   = blockIdx.y;           // 0:z 1:rate 2,3:hb halves
    const int col0 = by * 128;             // row offset into Wcat (512 rows)
    const int K    = 128;

    f32x4 acc[4][4];
    const f32x4 vzero = {0.f, 0.f, 0.f, 0.f};
    #pragma unroll
    for (int m = 0; m < 4; ++m)
        #pragma unroll
        for (int n = 0; n < 4; ++n) acc[m][n] = vzero;

    for (int kt = 0; kt < K; kt += 64) {
        #pragma unroll
        for (int c = 0; c < 4; ++c) {
            const int idx = c * 256 + tid;
            const int row = idx >> 3;
            const int gs  = (idx & 7) ^ (row & 7);
            __builtin_amdgcn_global_load_lds(
                (const __attribute__((address_space(1))) void*)(A + (size_t)(row0 + row) * K + kt + gs * 8),
                (__attribute__((address_space(3))) void*)(As + idx * 8), 16, 0, 0);
        }
        #pragma unroll
        for (int c = 0; c < 4; ++c) {
            const int idx = c * 256 + tid;
            const int row = idx >> 3;
            const int gs  = (idx & 7) ^ (row & 7);
            __builtin_amdgcn_global_load_lds(
                (const __attribute__((address_space(1))) void*)(Wcat + (size_t)(col0 + row) * K + kt + gs * 8),
                (__attribute__((address_space(3))) void*)(Bs + idx * 8), 16, 0, 0);
        }
        __syncthreads();

        #pragma unroll
        for (int kk = 0; kk < 2; ++kk) {
            const int gg = kk * 4 + (lane >> 4);
            sh8 a[4], b[4];
            #pragma unroll
            for (int m = 0; m < 4; ++m) {
                const int r = wr * 64 + m * 16 + (lane & 15);
                a[m] = *(const sh8*)(As + r * 64 + ((gg ^ (r & 7)) << 3));
            }
            #pragma unroll
            for (int n = 0; n < 4; ++n) {
                const int r = wc * 64 + n * 16 + (lane & 15);
                b[n] = *(const sh8*)(Bs + r * 64 + ((gg ^ (r & 7)) << 3));
            }
            #pragma unroll
            for (int m = 0; m < 4; ++m)
                #pragma unroll
                for (int n = 0; n < 4; ++n)
                    acc[m][n] = __builtin_amdgcn_mfma_f32_16x16x32_bf16(a[m], b[n], acc[m][n], 0, 0, 0);
        }
        __syncthreads();
    }

    // per-panel epilogue (all selects wave-uniform)
    unsigned short* dst;
    int ldc, cbase, mode;
    if (by == 0)      { dst = zbuf; ldc = 128; cbase = 0;   mode = 0; }
    else if (by == 1) { dst = rbuf; ldc = 128; cbase = 0;   mode = 1; }
    else              { dst = hbuf; ldc = 256; cbase = col0 - 256; mode = 2; }

    float bs[4];
    #pragma unroll
    for (int n = 0; n < 4; ++n) {
        const int cw = col0 + wc * 64 + n * 16 + (lane & 15);
        bs[n] = (mode == 0) ? b_fc[cw] : (mode == 2 ? b1[cw - 256] : 0.0f);
    }
    #pragma unroll
    for (int m = 0; m < 4; ++m) {
        #pragma unroll
        for (int r = 0; r < 4; ++r) {
            const int grow = row0 + wr * 64 + m * 16 + (lane >> 4) * 4 + r;
            #pragma unroll
            for (int n = 0; n < 4; ++n) {
                const int cdst = cbase + wc * 64 + n * 16 + (lane & 15);
                float v = acc[m][n][r] + bs[n];
                if (mode != 0) v = softplus_fast(v);
                dst[(size_t)grow * ldc + cdst] = f2b(v);
            }
        }
    }
}

// gpre: gpb = hb@W2^T + b2, K=256
__global__ __launch_bounds__(256)
void gemm_gpre(const unsigned short* __restrict__ A, const unsigned short* __restrict__ W,
               const float* __restrict__ bias, unsigned short* __restrict__ C16)
{
    __shared__ unsigned short As[128 * 64];
    __shared__ unsigned short Bs[128 * 64];
    const int tid  = threadIdx.x;
    const int lane = tid & 63;
    const int w    = tid >> 6;
    const int wr   = w >> 1, wc = w & 1;
    const int row0 = blockIdx.x * 128;
    const int K    = 256;

    f32x4 acc[4][4];
    const f32x4 vzero = {0.f, 0.f, 0.f, 0.f};
    #pragma unroll
    for (int m = 0; m < 4; ++m)
        #pragma unroll
        for (int n = 0; n < 4; ++n) acc[m][n] = vzero;

    for (int kt = 0; kt < K; kt += 64) {
        #pragma unroll
        for (int c = 0; c < 4; ++c) {
            const int idx = c * 256 + tid;
            const int row = idx >> 3;
            const int gs  = (idx & 7) ^ (row & 7);
            __builtin_amdgcn_global_load_lds(
                (const __attribute__((address_space(1))) void*)(A + (size_t)(row0 + row) * K + kt + gs * 8),
                (__attribute__((address_space(3))) void*)(As + idx * 8), 16, 0, 0);
        }
        #pragma unroll
        for (int c = 0; c < 4; ++c) {
            const int idx = c * 256 + tid;
            const int row = idx >> 3;
            const int gs  = (idx & 7) ^ (row & 7);
            __builtin_amdgcn_global_load_lds(
                (const __attribute__((address_space(1))) void*)(W + (size_t)row * K + kt + gs * 8),
                (__attribute__((address_space(3))) void*)(Bs + idx * 8), 16, 0, 0);
        }
        __syncthreads();

        #pragma unroll
        for (int kk = 0; kk < 2; ++kk) {
            const int gg = kk * 4 + (lane >> 4);
            sh8 a[4], b[4];
            #pragma unroll
            for (int m = 0; m < 4; ++m) {
                const int r = wr * 64 + m * 16 + (lane & 15);
                a[m] = *(const sh8*)(As + r * 64 + ((gg ^ (r & 7)) << 3));
            }
            #pragma unroll
            for (int n = 0; n < 4; ++n) {
                const int r = wc * 64 + n * 16 + (lane & 15);
                b[n] = *(const sh8*)(Bs + r * 64 + ((gg ^ (r & 7)) << 3));
            }
            #pragma unroll
            for (int m = 0; m < 4; ++m)
                #pragma unroll
                for (int n = 0; n < 4; ++n)
                    acc[m][n] = __builtin_amdgcn_mfma_f32_16x16x32_bf16(a[m], b[n], acc[m][n], 0, 0, 0);
        }
        __syncthreads();
    }

    float bs[4];
    #pragma unroll
    for (int n = 0; n < 4; ++n)
        bs[n] = bias[wc * 64 + n * 16 + (lane & 15)];
    #pragma unroll
    for (int m = 0; m < 4; ++m) {
        #pragma unroll
        for (int r = 0; r < 4; ++r) {
            const int grow = row0 + wr * 64 + m * 16 + (lane >> 4) * 4 + r;
            #pragma unroll
            for (int n = 0; n < 4; ++n) {
                const int cdst = wc * 64 + n * 16 + (lane & 15);
                C16[(size_t)grow * 128 + cdst] = f2b(acc[m][n][r] + bs[n]);
            }
        }
    }
}

// ---------------- edge CSR build ----------------
__global__ void count_edges(const int* __restrict__ ei, int E, int* __restrict__ cnt) {
    for (int e = blockIdx.x * blockDim.x + threadIdx.x; e < E; e += gridDim.x * blockDim.x)
        atomicAdd(&cnt[ei[e]], 1);
}

__global__ void scan_part(const int* __restrict__ cnt, int n, int* __restrict__ part) {
    __shared__ int sdata[256];
    const int base = blockIdx.x * 1024;
    int s = 0;
    for (int i = threadIdx.x; i < 1024; i += 256) {
        const int idx = base + i;
        s += (idx < n) ? cnt[idx] : 0;
    }
    sdata[threadIdx.x] = s;
    __syncthreads();
    for (int st = 128; st > 0; st >>= 1) {
        if (threadIdx.x < st) sdata[threadIdx.x] += sdata[threadIdx.x + st];
        __syncthreads();
    }
    if (threadIdx.x == 0) part[blockIdx.x] = sdata[0];
}

__global__ __launch_bounds__(256)
void scan_top(int* __restrict__ part, int nb) {
    __shared__ int sums[256];
    const int tid = threadIdx.x;
    int v[4]; int s = 0;
    #pragma unroll
    for (int i = 0; i < 4; ++i) {
        const int idx = tid * 4 + i;
        v[i] = (idx < nb) ? part[idx] : 0;
        s += v[i];
    }
    sums[tid] = s;
    __syncthreads();
    for (int st = 1; st < 256; st <<= 1) {
        const int t = (tid >= st) ? sums[tid - st] : 0;
        __syncthreads();
        sums[tid] += t;
        __syncthreads();
    }
    int excl = sums[tid] - s;
    #pragma unroll
    for (int i = 0; i < 4; ++i) {
        const int idx = tid * 4 + i;
        if (idx < nb) part[idx] = excl;
        excl += v[i];
    }
}

__global__ void scan_final(const int* __restrict__ cnt, int n,
                           const int* __restrict__ part, int* __restrict__ offs) {
    __shared__ int sums[256];
    const int tid = threadIdx.x;
    const int base = blockIdx.x * 1024 + tid * 4;
    int v[4]; int s = 0;
    #pragma unroll
    for (int i = 0; i < 4; ++i) {
        const int idx = base + i;
        v[i] = (idx < n) ? cnt[idx] : 0;
        s += v[i];
    }
    sums[tid] = s;
    __syncthreads();
    for (int st = 1; st < 256; st <<= 1) {
        const int t = (tid >= st) ? sums[tid - st] : 0;
        __syncthreads();
        sums[tid] += t;
        __syncthreads();
    }
    int excl = part[blockIdx.x] + sums[tid] - s;
    #pragma unroll
    for (int i = 0; i < 4; ++i) {
        const int idx = base + i;
        if (idx < n) offs[idx] = excl;
        excl += v[i];
    }
}

__global__ void fill_edges(const int* __restrict__ ei, int E, const int* __restrict__ offs,
                           int* __restrict__ cur, int* __restrict__ bucket) {
    for (int e = blockIdx.x * blockDim.x + threadIdx.x; e < E; e += gridDim.x * blockDim.x) {
        const int r = ei[e];
        const int p = atomicAdd(&cur[r], 1);
        bucket[offs[r] + p] = ei[E + e];
    }
}

// ---------------- fused tail: LN1 + gather + combine + LN2 ----------------
__device__ __forceinline__ float wave_allreduce_sum(float v) {
    #pragma unroll
    for (int m = 1; m < 64; m <<= 1) v += __shfl_xor(v, m, 64);
    return v;
}

__global__ __launch_bounds__(256)
void final_fused(const unsigned short* __restrict__ zb, const unsigned short* __restrict__ rtb,
                 const unsigned short* __restrict__ gpb, const float* __restrict__ degree,
                 const int* __restrict__ cnt, const int* __restrict__ offs,
                 const int* __restrict__ bucket,
                 const float* __restrict__ ln1g, const float* __restrict__ ln1b,
                 const float* __restrict__ ln2g, const float* __restrict__ ln2b,
                 float* __restrict__ out, int n)
{
    const int lane = threadIdx.x & 63;
    const int node = blockIdx.x * 4 + (threadIdx.x >> 6);
    if (node >= n) return;

    const unsigned int uz = ((const unsigned int*)(zb  + (size_t)node * 128))[lane];
    const unsigned int ur = ((const unsigned int*)(rtb + (size_t)node * 128))[lane];
    const unsigned int ug = ((const unsigned int*)(gpb + (size_t)node * 128))[lane];
    const float zx = b2lo(uz), zy = b2hi(uz);
    const float rx = b2lo(ur), ry = b2hi(ur);
    const float px = b2lo(ug), py = b2hi(ug);

    // LayerNorm 1 -> gamma
    float mean = wave_allreduce_sum(px + py) * (1.0f / 128.0f);
    float d0 = px - mean, d1 = py - mean;
    float var = wave_allreduce_sum(d0 * d0 + d1 * d1) * (1.0f / 128.0f);
    float rstd = rsqrtf(var + 1e-5f);
    const float2 g1 = ((const float2*)ln1g)[lane];
    const float2 b1 = ((const float2*)ln1b)[lane];
    const float gmx = d0 * rstd * g1.x + b1.x;
    const float gmy = d1 * rstd * g1.y + b1.y;

    // aggregate: cnt*z[node] + sum zb[col]  (4x unrolled, 2 acc pairs for MLP)
    const int c    = cnt[node];
    const int o0   = offs[node];
    const int jend = o0 + c;
    float ax = (float)c * zx, ay = (float)c * zy;
    float bx = 0.0f, by = 0.0f;
    int j = o0;
    for (; j + 4 <= jend; j += 4) {
        const int c0 = bucket[j + 0];
        const int c1 = bucket[j + 1];
        const int c2 = bucket[j + 2];
        const int c3 = bucket[j + 3];
        const unsigned int u0 = ((const unsigned int*)(zb + (size_t)c0 * 128))[lane];
        const unsigned int u1 = ((const unsigned int*)(zb + (size_t)c1 * 128))[lane];
        const unsigned int u2 = ((const unsigned int*)(zb + (size_t)c2 * 128))[lane];
        const unsigned int u3 = ((const unsigned int*)(zb + (size_t)c3 * 128))[lane];
        ax += b2lo(u0) + b2lo(u2);
        ay += b2hi(u0) + b2hi(u2);
        bx += b2lo(u1) + b2lo(u3);
        by += b2hi(u1) + b2hi(u3);
    }
    for (; j < jend; ++j) {
        const int c0 = bucket[j];
        const unsigned int u0 = ((const unsigned int*)(zb + (size_t)c0 * 128))[lane];
        ax += b2lo(u0);
        ay += b2hi(u0);
    }
    ax += bx; ay += by;

    const float dg = degree[node];
    float ox = (rx * ax + gmx) / (1.0f + rx * dg + 1e-4f) - zx;
    float oy = (ry * ay + gmy) / (1.0f + ry * dg + 1e-4f) - zy;

    // LayerNorm 2
    mean = wave_allreduce_sum(ox + oy) * (1.0f / 128.0f);
    d0 = ox - mean; d1 = oy - mean;
    var = wave_allreduce_sum(d0 * d0 + d1 * d1) * (1.0f / 128.0f);
    rstd = rsqrtf(var + 1e-5f);
    const float2 g2 = ((const float2*)ln2g)[lane];
    const float2 b2 = ((const float2*)ln2b)[lane];
    float2 res;
    res.x = d0 * rstd * g2.x + b2.x;
    res.y = d1 * rstd * g2.y + b2.y;
    ((float2*)(out + (size_t)node * 128))[lane] = res;
}

// ---------------------------------------------------------------------------
extern "C" void kernel_launch(void* const* d_in, const int* in_sizes, int n_in,
                              void* d_out, int out_size, void* d_ws, size_t ws_size,
                              hipStream_t stream)
{
    const float* x    = (const float*)d_in[0];
    const int*   ei   = (const int*)  d_in[1];
    const float* deg  = (const float*)d_in[2];
    const float* W_fc = (const float*)d_in[3];
    const float* b_fc = (const float*)d_in[4];
    const float* W_rt = (const float*)d_in[5];
    const float* W1   = (const float*)d_in[6];
    const float* b1   = (const float*)d_in[7];
    const float* W2   = (const float*)d_in[8];
    const float* b2   = (const float*)d_in[9];
    const float* ln1g = (const float*)d_in[10];
    const float* ln1b = (const float*)d_in[11];
    const float* ln2g = (const float*)d_in[12];
    const float* ln2b = (const float*)d_in[13];

    const int N  = in_sizes[0] / 128;
    const int E  = in_sizes[1] / 2;
    const int N2 = ((N + 127) / 128) * 128;     // padded rows
    const int gx = N2 / 128;
    float* out = (float*)d_out;

    // workspace carve (16B-aligned by construction)
    char* p = (char*)d_ws;
    unsigned short* xb  = (unsigned short*)p;  p += (size_t)N2 * 128 * 2;
    unsigned short* hb  = (unsigned short*)p;  p += (size_t)N2 * 256 * 2;
    unsigned short* zb  = (unsigned short*)p;  p += (size_t)N2 * 128 * 2;
    unsigned short* rtb = (unsigned short*)p;  p += (size_t)N2 * 128 * 2;
    unsigned short* gpb = (unsigned short*)p;  p += (size_t)N2 * 128 * 2;
    unsigned short* wb  = (unsigned short*)p;  p += 98304 * 2;
    int* cnt    = (int*)p;                     p += (size_t)N * sizeof(int);
    int* cur    = (int*)p;                     p += (size_t)N * sizeof(int);
    int* offs   = (int*)p;                     p += (size_t)(N + 1) * sizeof(int);
    int* part   = (int*)p;                     p += 1024 * sizeof(int);
    int* bucket = (int*)p;

    const int nb = (N + 1023) / 1024;

    // edge CSR build (cnt & cur adjacent -> one memset)
    hipMemsetAsync(cnt, 0, (size_t)2 * N * sizeof(int), stream);
    count_edges<<<2048, 256, 0, stream>>>(ei, E, cnt);
    scan_part <<<nb, 256, 0, stream>>>(cnt, N, part);
    scan_top  <<<1, 256, 0, stream>>>(part, nb);
    scan_final<<<nb, 256, 0, stream>>>(cnt, N, part, offs);
    fill_edges<<<2048, 256, 0, stream>>>(ei, E, offs, cur, bucket);

    // bf16 conversions
    convert_pad    <<<2048, 256, 0, stream>>>(x, xb, (long long)N * 128, (long long)N2 * 128);
    convert_weights<<<384, 256, 0, stream>>>(W_fc, W_rt, W1, W2, wb);

    // GEMMs: fused z/rate/hb panels, then gpre
    gemm_fused3<<<dim3(gx, 4), 256, 0, stream>>>(xb, wb, b_fc, b1, zb, rtb, hb);
    gemm_gpre  <<<dim3(gx, 1), 256, 0, stream>>>(hb, wb + 65536, b2, gpb);

    final_fused<<<(N + 3) / 4, 256, 0, stream>>>(zb, rtb, gpb, deg, cnt, offs, bucket,
                                                 ln1g, ln1b, ln2g, ln2b, out, N);
}

// Round 9
// 442.715 us; speedup vs baseline: 2.0062x; 1.0166x over previous
//
#include <hip/hip_runtime.h>
#include <hip/hip_bf16.h>
#include <stdint.h>

// ---------------------------------------------------------------------------
// BoundaryConvLayer — round 8 (resubmit): single-pass GEMM front-end.
//   gemm_fused4: per 128-row block, stage x-tile ONCE (fp32->bf16 in-reg,
//   swizzled ds_write), then loop 4 weight panels (z | rate | h0 | h1),
//   staging 16 KB B-tiles per K-step. Removes convert_pad + xb + 3/4 of
//   A-staging. gpre / final_fused / CSR byte-identical to round 7.
//   zb   = xb@Wfc^T + b_fc          [N2 x 128] bf16
//   rtb  = softplus(xb@Wrt^T)       [N2 x 128] bf16
//   hb   = softplus(xb@W1^T + b1)   [N2 x 256] bf16
//   gpb  = hb@W2^T + b2             [N2 x 128] bf16
//   agg[r] = cnt[r]*zb[r] + sum_{edges row=r} zb[col]
//   out  = LN2( (rtb*agg + LN1(gpb)) / (1 + rtb*deg + 1e-4) - zb )  (fp32)
// ---------------------------------------------------------------------------

typedef __attribute__((ext_vector_type(8))) short  sh8;
typedef __attribute__((ext_vector_type(4))) float  f32x4;

// fast softplus: hw v_exp_f32 / v_log_f32 (~8 VALU ops, |err| ~1e-6)
__device__ __forceinline__ float softplus_fast(float v) {
    const float t = __expf(-fabsf(v));
    return fmaxf(v, 0.0f) + __logf(1.0f + t);
}
// manual round-to-nearest-even bf16 pack (4 VALU ops, no libm)
__device__ __forceinline__ unsigned short f2b(float f) {
    unsigned int u = __float_as_uint(f);
    u += 0x7fffu + ((u >> 16) & 1u);
    return (unsigned short)(u >> 16);
}
__device__ __forceinline__ float b2lo(unsigned int u) {
    return __uint_as_float(u << 16);
}
__device__ __forceinline__ float b2hi(unsigned int u) {
    return __uint_as_float(u & 0xffff0000u);
}

// ---------------- weight conversion ----------------
__global__ __launch_bounds__(256)
void convert_weights(const float* __restrict__ Wfc, const float* __restrict__ Wrt,
                     const float* __restrict__ W1,  const float* __restrict__ W2,
                     unsigned short* __restrict__ wb)
{
    const int i = blockIdx.x * blockDim.x + threadIdx.x;   // 0..98303
    float v;
    if (i < 16384)       v = Wfc[i];
    else if (i < 32768)  v = Wrt[i - 16384];
    else if (i < 65536)  v = W1[i - 32768];
    else                 v = W2[i - 65536];
    wb[i] = f2b(v);
}

// ---------------- fused front GEMM: z, rate, h from one x-tile -------------
// 128x128 output tile per panel, BK=64, 4 waves, mfma_f32_16x16x32_bf16.
// x staged once: fp32 -> bf16 -> LDS with granule XOR swizzle on the WRITE
// side; B panels staged per K-step via global_load_lds (linear dest,
// source-side XOR); both read sides apply the matching XOR (rule 21).
__global__ __launch_bounds__(256)
void gemm_fused4(const float* __restrict__ x, const unsigned short* __restrict__ Wcat,
                 const float* __restrict__ b_fc, const float* __restrict__ b1,
                 unsigned short* __restrict__ zbuf, unsigned short* __restrict__ rbuf,
                 unsigned short* __restrict__ hbuf, int nrows)
{
    __shared__ unsigned short Xs[128 * 128];   // 32 KB, full K=128
    __shared__ unsigned short Bs[128 * 64];    // 16 KB per K-step
    const int tid  = threadIdx.x;
    const int lane = tid & 63;
    const int w    = tid >> 6;
    const int wr   = w >> 1, wc = w & 1;       // 2x2 wave grid, 64x64 per wave
    const int row0 = blockIdx.x * 128;

    // ---- stage x-tile once: 2048 granules of 16 B ----
    #pragma unroll
    for (int c = 0; c < 8; ++c) {
        const int idx = c * 256 + tid;         // 0..2047
        const int row = idx >> 4;              // 0..127
        const int g   = idx & 15;              // source granule (8 floats)
        const int ga  = row0 + row;
        sh8 v;
        if (ga < nrows) {
            const float4 f0 = *(const float4*)(x + (size_t)ga * 128 + g * 8);
            const float4 f1 = *(const float4*)(x + (size_t)ga * 128 + g * 8 + 4);
            v[0] = (short)f2b(f0.x); v[1] = (short)f2b(f0.y);
            v[2] = (short)f2b(f0.z); v[3] = (short)f2b(f0.w);
            v[4] = (short)f2b(f1.x); v[5] = (short)f2b(f1.y);
            v[6] = (short)f2b(f1.z); v[7] = (short)f2b(f1.w);
        } else {
            v = (sh8)(short)0;
        }
        *(sh8*)(Xs + (row * 16 + (g ^ (row & 7))) * 8) = v;   // write-side XOR
    }

    for (int p = 0; p < 4; ++p) {              // 0:z 1:rate 2,3:h halves
        f32x4 acc[4][4];
        const f32x4 vzero = {0.f, 0.f, 0.f, 0.f};
        #pragma unroll
        for (int m = 0; m < 4; ++m)
            #pragma unroll
            for (int n = 0; n < 4; ++n) acc[m][n] = vzero;

        for (int kt = 0; kt < 128; kt += 64) {
            __syncthreads();                   // prev compute done (1st: Xs visible)
            #pragma unroll
            for (int c = 0; c < 4; ++c) {
                const int idx  = c * 256 + tid;        // 0..1023
                const int brow = idx >> 3;
                const int gs   = (idx & 7) ^ (brow & 7);
                __builtin_amdgcn_global_load_lds(
                    (const __attribute__((address_space(1))) void*)(Wcat + (size_t)(p * 128 + brow) * 128 + kt + gs * 8),
                    (__attribute__((address_space(3))) void*)(Bs + idx * 8), 16, 0, 0);
            }
            __syncthreads();                   // staging complete

            const int gb = kt >> 3;            // 0 or 8
            #pragma unroll
            for (int kk = 0; kk < 2; ++kk) {
                const int gg = kk * 4 + (lane >> 4);   // 0..7 within K-step
                sh8 a[4], b[4];
                #pragma unroll
                for (int m = 0; m < 4; ++m) {
                    const int r = wr * 64 + m * 16 + (lane & 15);
                    a[m] = *(const sh8*)(Xs + (r * 16 + ((gb + gg) ^ (r & 7))) * 8);
                }
                #pragma unroll
                for (int n = 0; n < 4; ++n) {
                    const int r = wc * 64 + n * 16 + (lane & 15);
                    b[n] = *(const sh8*)(Bs + r * 64 + ((gg ^ (r & 7)) << 3));
                }
                #pragma unroll
                for (int m = 0; m < 4; ++m)
                    #pragma unroll
                    for (int n = 0; n < 4; ++n)
                        acc[m][n] = __builtin_amdgcn_mfma_f32_16x16x32_bf16(a[m], b[n], acc[m][n], 0, 0, 0);
            }
        }

        // ---- per-panel epilogue (wave-uniform selects) ----
        unsigned short* dst;
        int ldc, cbase, sp;
        if (p == 0)      { dst = zbuf; ldc = 128; cbase = 0;             sp = 0; }
        else if (p == 1) { dst = rbuf; ldc = 128; cbase = 0;             sp = 1; }
        else             { dst = hbuf; ldc = 256; cbase = (p - 2) * 128; sp = 1; }

        float bs[4];
        #pragma unroll
        for (int n = 0; n < 4; ++n) {
            const int cw = wc * 64 + n * 16 + (lane & 15);
            bs[n] = (p == 0) ? b_fc[cw] : ((p >= 2) ? b1[cbase + cw] : 0.0f);
        }
        #pragma unroll
        for (int m = 0; m < 4; ++m) {
            #pragma unroll
            for (int r = 0; r < 4; ++r) {
                const int grow = row0 + wr * 64 + m * 16 + (lane >> 4) * 4 + r;
                #pragma unroll
                for (int n = 0; n < 4; ++n) {
                    const int cdst = cbase + wc * 64 + n * 16 + (lane & 15);
                    float v = acc[m][n][r] + bs[n];
                    if (sp) v = softplus_fast(v);
                    dst[(size_t)grow * ldc + cdst] = f2b(v);
                }
            }
        }
    }
}

// gpre: gpb = hb@W2^T + b2, K=256  (byte-identical to round 7)
__global__ __launch_bounds__(256)
void gemm_gpre(const unsigned short* __restrict__ A, const unsigned short* __restrict__ W,
               const float* __restrict__ bias, unsigned short* __restrict__ C16)
{
    __shared__ unsigned short As[128 * 64];
    __shared__ unsigned short Bs[128 * 64];
    const int tid  = threadIdx.x;
    const int lane = tid & 63;
    const int w    = tid >> 6;
    const int wr   = w >> 1, wc = w & 1;
    const int row0 = blockIdx.x * 128;
    const int K    = 256;

    f32x4 acc[4][4];
    const f32x4 vzero = {0.f, 0.f, 0.f, 0.f};
    #pragma unroll
    for (int m = 0; m < 4; ++m)
        #pragma unroll
        for (int n = 0; n < 4; ++n) acc[m][n] = vzero;

    for (int kt = 0; kt < K; kt += 64) {
        #pragma unroll
        for (int c = 0; c < 4; ++c) {
            const int idx = c * 256 + tid;
            const int row = idx >> 3;
            const int gs  = (idx & 7) ^ (row & 7);
            __builtin_amdgcn_global_load_lds(
                (const __attribute__((address_space(1))) void*)(A + (size_t)(row0 + row) * K + kt + gs * 8),
                (__attribute__((address_space(3))) void*)(As + idx * 8), 16, 0, 0);
        }
        #pragma unroll
        for (int c = 0; c < 4; ++c) {
            const int idx = c * 256 + tid;
            const int row = idx >> 3;
            const int gs  = (idx & 7) ^ (row & 7);
            __builtin_amdgcn_global_load_lds(
                (const __attribute__((address_space(1))) void*)(W + (size_t)row * K + kt + gs * 8),
                (__attribute__((address_space(3))) void*)(Bs + idx * 8), 16, 0, 0);
        }
        __syncthreads();

        #pragma unroll
        for (int kk = 0; kk < 2; ++kk) {
            const int gg = kk * 4 + (lane >> 4);
            sh8 a[4], b[4];
            #pragma unroll
            for (int m = 0; m < 4; ++m) {
                const int r = wr * 64 + m * 16 + (lane & 15);
                a[m] = *(const sh8*)(As + r * 64 + ((gg ^ (r & 7)) << 3));
            }
            #pragma unroll
            for (int n = 0; n < 4; ++n) {
                const int r = wc * 64 + n * 16 + (lane & 15);
                b[n] = *(const sh8*)(Bs + r * 64 + ((gg ^ (r & 7)) << 3));
            }
            #pragma unroll
            for (int m = 0; m < 4; ++m)
                #pragma unroll
                for (int n = 0; n < 4; ++n)
                    acc[m][n] = __builtin_amdgcn_mfma_f32_16x16x32_bf16(a[m], b[n], acc[m][n], 0, 0, 0);
        }
        __syncthreads();
    }

    float bs[4];
    #pragma unroll
    for (int n = 0; n < 4; ++n)
        bs[n] = bias[wc * 64 + n * 16 + (lane & 15)];
    #pragma unroll
    for (int m = 0; m < 4; ++m) {
        #pragma unroll
        for (int r = 0; r < 4; ++r) {
            const int grow = row0 + wr * 64 + m * 16 + (lane >> 4) * 4 + r;
            #pragma unroll
            for (int n = 0; n < 4; ++n) {
                const int cdst = wc * 64 + n * 16 + (lane & 15);
                C16[(size_t)grow * 128 + cdst] = f2b(acc[m][n][r] + bs[n]);
            }
        }
    }
}

// ---------------- edge CSR build ----------------
__global__ void count_edges(const int* __restrict__ ei, int E, int* __restrict__ cnt) {
    for (int e = blockIdx.x * blockDim.x + threadIdx.x; e < E; e += gridDim.x * blockDim.x)
        atomicAdd(&cnt[ei[e]], 1);
}

__global__ void scan_part(const int* __restrict__ cnt, int n, int* __restrict__ part) {
    __shared__ int sdata[256];
    const int base = blockIdx.x * 1024;
    int s = 0;
    for (int i = threadIdx.x; i < 1024; i += 256) {
        const int idx = base + i;
        s += (idx < n) ? cnt[idx] : 0;
    }
    sdata[threadIdx.x] = s;
    __syncthreads();
    for (int st = 128; st > 0; st >>= 1) {
        if (threadIdx.x < st) sdata[threadIdx.x] += sdata[threadIdx.x + st];
        __syncthreads();
    }
    if (threadIdx.x == 0) part[blockIdx.x] = sdata[0];
}

__global__ __launch_bounds__(256)
void scan_top(int* __restrict__ part, int nb) {
    __shared__ int sums[256];
    const int tid = threadIdx.x;
    int v[4]; int s = 0;
    #pragma unroll
    for (int i = 0; i < 4; ++i) {
        const int idx = tid * 4 + i;
        v[i] = (idx < nb) ? part[idx] : 0;
        s += v[i];
    }
    sums[tid] = s;
    __syncthreads();
    for (int st = 1; st < 256; st <<= 1) {
        const int t = (tid >= st) ? sums[tid - st] : 0;
        __syncthreads();
        sums[tid] += t;
        __syncthreads();
    }
    int excl = sums[tid] - s;
    #pragma unroll
    for (int i = 0; i < 4; ++i) {
        const int idx = tid * 4 + i;
        if (idx < nb) part[idx] = excl;
        excl += v[i];
    }
}

__global__ void scan_final(const int* __restrict__ cnt, int n,
                           const int* __restrict__ part, int* __restrict__ offs) {
    __shared__ int sums[256];
    const int tid = threadIdx.x;
    const int base = blockIdx.x * 1024 + tid * 4;
    int v[4]; int s = 0;
    #pragma unroll
    for (int i = 0; i < 4; ++i) {
        const int idx = base + i;
        v[i] = (idx < n) ? cnt[idx] : 0;
        s += v[i];
    }
    sums[tid] = s;
    __syncthreads();
    for (int st = 1; st < 256; st <<= 1) {
        const int t = (tid >= st) ? sums[tid - st] : 0;
        __syncthreads();
        sums[tid] += t;
        __syncthreads();
    }
    int excl = part[blockIdx.x] + sums[tid] - s;
    #pragma unroll
    for (int i = 0; i < 4; ++i) {
        const int idx = base + i;
        if (idx < n) offs[idx] = excl;
        excl += v[i];
    }
}

__global__ void fill_edges(const int* __restrict__ ei, int E, const int* __restrict__ offs,
                           int* __restrict__ cur, int* __restrict__ bucket) {
    for (int e = blockIdx.x * blockDim.x + threadIdx.x; e < E; e += gridDim.x * blockDim.x) {
        const int r = ei[e];
        const int p = atomicAdd(&cur[r], 1);
        bucket[offs[r] + p] = ei[E + e];
    }
}

// ---------------- fused tail: LN1 + gather + combine + LN2 -----------------
__device__ __forceinline__ float wave_allreduce_sum(float v) {
    #pragma unroll
    for (int m = 1; m < 64; m <<= 1) v += __shfl_xor(v, m, 64);
    return v;
}

__global__ __launch_bounds__(256)
void final_fused(const unsigned short* __restrict__ zb, const unsigned short* __restrict__ rtb,
                 const unsigned short* __restrict__ gpb, const float* __restrict__ degree,
                 const int* __restrict__ cnt, const int* __restrict__ offs,
                 const int* __restrict__ bucket,
                 const float* __restrict__ ln1g, const float* __restrict__ ln1b,
                 const float* __restrict__ ln2g, const float* __restrict__ ln2b,
                 float* __restrict__ out, int n)
{
    const int lane = threadIdx.x & 63;
    const int node = blockIdx.x * 4 + (threadIdx.x >> 6);
    if (node >= n) return;

    const unsigned int uz = ((const unsigned int*)(zb  + (size_t)node * 128))[lane];
    const unsigned int ur = ((const unsigned int*)(rtb + (size_t)node * 128))[lane];
    const unsigned int ug = ((const unsigned int*)(gpb + (size_t)node * 128))[lane];
    const float zx = b2lo(uz), zy = b2hi(uz);
    const float rx = b2lo(ur), ry = b2hi(ur);
    const float px = b2lo(ug), py = b2hi(ug);

    // LayerNorm 1 -> gamma
    float mean = wave_allreduce_sum(px + py) * (1.0f / 128.0f);
    float d0 = px - mean, d1 = py - mean;
    float var = wave_allreduce_sum(d0 * d0 + d1 * d1) * (1.0f / 128.0f);
    float rstd = rsqrtf(var + 1e-5f);
    const float2 g1 = ((const float2*)ln1g)[lane];
    const float2 b1 = ((const float2*)ln1b)[lane];
    const float gmx = d0 * rstd * g1.x + b1.x;
    const float gmy = d1 * rstd * g1.y + b1.y;

    // aggregate: cnt*z[node] + sum zb[col]  (4x unrolled, 2 acc pairs for MLP)
    const int c    = cnt[node];
    const int o0   = offs[node];
    const int jend = o0 + c;
    float ax = (float)c * zx, ay = (float)c * zy;
    float bx = 0.0f, by = 0.0f;
    int j = o0;
    for (; j + 4 <= jend; j += 4) {
        const int c0 = bucket[j + 0];
        const int c1 = bucket[j + 1];
        const int c2 = bucket[j + 2];
        const int c3 = bucket[j + 3];
        const unsigned int u0 = ((const unsigned int*)(zb + (size_t)c0 * 128))[lane];
        const unsigned int u1 = ((const unsigned int*)(zb + (size_t)c1 * 128))[lane];
        const unsigned int u2 = ((const unsigned int*)(zb + (size_t)c2 * 128))[lane];
        const unsigned int u3 = ((const unsigned int*)(zb + (size_t)c3 * 128))[lane];
        ax += b2lo(u0) + b2lo(u2);
        ay += b2hi(u0) + b2hi(u2);
        bx += b2lo(u1) + b2lo(u3);
        by += b2hi(u1) + b2hi(u3);
    }
    for (; j < jend; ++j) {
        const int c0 = bucket[j];
        const unsigned int u0 = ((const unsigned int*)(zb + (size_t)c0 * 128))[lane];
        ax += b2lo(u0);
        ay += b2hi(u0);
    }
    ax += bx; ay += by;

    const float dg = degree[node];
    float ox = (rx * ax + gmx) / (1.0f + rx * dg + 1e-4f) - zx;
    float oy = (ry * ay + gmy) / (1.0f + ry * dg + 1e-4f) - zy;

    // LayerNorm 2
    mean = wave_allreduce_sum(ox + oy) * (1.0f / 128.0f);
    d0 = ox - mean; d1 = oy - mean;
    var = wave_allreduce_sum(d0 * d0 + d1 * d1) * (1.0f / 128.0f);
    rstd = rsqrtf(var + 1e-5f);
    const float2 g2 = ((const float2*)ln2g)[lane];
    const float2 b2 = ((const float2*)ln2b)[lane];
    float2 res;
    res.x = d0 * rstd * g2.x + b2.x;
    res.y = d1 * rstd * g2.y + b2.y;
    ((float2*)(out + (size_t)node * 128))[lane] = res;
}

// ---------------------------------------------------------------------------
extern "C" void kernel_launch(void* const* d_in, const int* in_sizes, int n_in,
                              void* d_out, int out_size, void* d_ws, size_t ws_size,
                              hipStream_t stream)
{
    const float* x    = (const float*)d_in[0];
    const int*   ei   = (const int*)  d_in[1];
    const float* deg  = (const float*)d_in[2];
    const float* W_fc = (const float*)d_in[3];
    const float* b_fc = (const float*)d_in[4];
    const float* W_rt = (const float*)d_in[5];
    const float* W1   = (const float*)d_in[6];
    const float* b1   = (const float*)d_in[7];
    const float* W2   = (const float*)d_in[8];
    const float* b2   = (const float*)d_in[9];
    const float* ln1g = (const float*)d_in[10];
    const float* ln1b = (const float*)d_in[11];
    const float* ln2g = (const float*)d_in[12];
    const float* ln2b = (const float*)d_in[13];

    const int N  = in_sizes[0] / 128;
    const int E  = in_sizes[1] / 2;
    const int N2 = ((N + 127) / 128) * 128;     // padded rows
    const int gx = N2 / 128;
    float* out = (float*)d_out;

    // workspace carve (16B-aligned by construction)
    char* p = (char*)d_ws;
    unsigned short* hb  = (unsigned short*)p;  p += (size_t)N2 * 256 * 2;
    unsigned short* zb  = (unsigned short*)p;  p += (size_t)N2 * 128 * 2;
    unsigned short* rtb = (unsigned short*)p;  p += (size_t)N2 * 128 * 2;
    unsigned short* gpb = (unsigned short*)p;  p += (size_t)N2 * 128 * 2;
    unsigned short* wb  = (unsigned short*)p;  p += 98304 * 2;
    int* cnt    = (int*)p;                     p += (size_t)N * sizeof(int);
    int* cur    = (int*)p;                     p += (size_t)N * sizeof(int);
    int* offs   = (int*)p;                     p += (size_t)(N + 1) * sizeof(int);
    int* part   = (int*)p;                     p += 1024 * sizeof(int);
    int* bucket = (int*)p;

    const int nb = (N + 1023) / 1024;

    // edge CSR build (cnt & cur adjacent -> one memset)
    hipMemsetAsync(cnt, 0, (size_t)2 * N * sizeof(int), stream);
    count_edges<<<2048, 256, 0, stream>>>(ei, E, cnt);
    scan_part <<<nb, 256, 0, stream>>>(cnt, N, part);
    scan_top  <<<1, 256, 0, stream>>>(part, nb);
    scan_final<<<nb, 256, 0, stream>>>(cnt, N, part, offs);
    fill_edges<<<2048, 256, 0, stream>>>(ei, E, offs, cur, bucket);

    // weight conversion
    convert_weights<<<384, 256, 0, stream>>>(W_fc, W_rt, W1, W2, wb);

    // GEMMs: fused z/rate/h (x staged once per block), then gpre
    gemm_fused4<<<gx, 256, 0, stream>>>(x, wb, b_fc, b1, zb, rtb, hb, N);
    gemm_gpre  <<<gx, 256, 0, stream>>>(hb, wb + 65536, b2, gpb);

    final_fused<<<(N + 3) / 4, 256, 0, stream>>>(zb, rtb, gpb, deg, cnt, offs, bucket,
                                                 ln1g, ln1b, ln2g, ln2b, out, N);
}